// Round 5
// baseline (445.732 us; speedup 1.0000x reference)
//
#include <hip/hip_runtime.h>

typedef unsigned short u16;
typedef __bf16 bf16x8 __attribute__((ext_vector_type(8)));
typedef unsigned short us8 __attribute__((ext_vector_type(8)));
typedef float f32x4 __attribute__((ext_vector_type(4)));
typedef float f32x2 __attribute__((ext_vector_type(2)));
typedef unsigned int u32x4 __attribute__((ext_vector_type(4)));

union U8u { us8 s; u16 u[8]; };

__device__ __forceinline__ u16 f2bf(float f){
  unsigned u = __builtin_bit_cast(unsigned, f);
  u += 0x7fffu + ((u >> 16) & 1u);
  return (u16)(u >> 16);
}
__device__ __forceinline__ bf16x8 asbf(us8 x){ return __builtin_bit_cast(bf16x8, x); }

#define MFMA16(a,b,c) __builtin_amdgcn_mfma_f32_16x16x32_bf16((a),(b),(c),0,0,0)

// ---------------------------------------------------------------------------
// Conv: 3x3 SAME on 17x17, Cin=64, im2col GEMM, K' = tap*64 + cin.
// LDS sS: PIXEL-major zero-padded [19*19][72] bf16; sW: [cout 16][584] bf16.
// h workspace is PIXEL-major [b][pix][64] so conv2 staging is a straight copy.
// ---------------------------------------------------------------------------
__device__ __forceinline__ void stage_zero2(u16* sS, int tid){
  uint* z = (uint*)sS;
  for (int i = tid; i < 12996; i += 256) z[i] = 0u;   // 361*72 u16
}

__device__ __forceinline__ void stage_src_f32T(const float* __restrict__ src,
                                               u16* sS, int tid){
  for (int i4 = tid; i4 < 4624; i4 += 256){           // 64*289/4
    int e = i4 * 4;
    f32x4 dv = *(const f32x4*)(src + e);
    #pragma unroll
    for (int t = 0; t < 4; t++){
      int ee = e + t;
      int ci = ee / 289; int rr = ee - ci*289;
      int oy = rr / 17;  int ox = rr - oy*17;
      sS[((oy+1)*19 + ox+1)*72 + ci] = f2bf(dv[t]);
    }
  }
}

// pixel-major bf16 source [pix][64] -> one us8 load + one ds_write_b128 per 8
__device__ __forceinline__ void stage_src_pm(const u16* __restrict__ src,
                                             u16* sS, int tid){
  for (int i8 = tid; i8 < 2312; i8 += 256){           // 289*64/8
    int pix = i8 >> 3, c0 = (i8 & 7) << 3;
    us8 v = *(const us8*)(src + ((size_t)pix << 6) + c0);
    int oy = pix / 17, ox = pix - oy*17;
    *(us8*)(sS + ((oy+1)*19 + ox+1)*72 + c0) = v;
  }
}

__device__ __forceinline__ void stage_w_f32(const float* __restrict__ w, int m0,
                                            u16* sW, int tid){
  for (int i4 = tid; i4 < 2304; i4 += 256){           // 16*576/4
    int e = i4 * 4;
    int co = e / 576; int r0 = e - co*576;
    f32x4 wv = *(const f32x4*)(w + (size_t)(m0+co)*576 + r0);
    #pragma unroll
    for (int t = 0; t < 4; t++){
      int r = r0 + t; int cin = r / 9; int tap = r - cin*9;
      sW[co*584 + tap*64 + cin] = f2bf(wv[t]);
    }
  }
}

__device__ __forceinline__ f32x4 conv_tile2(const u16* sS, const u16* sW,
                                            int nt, int l15, int q)
{
  int p = nt*16 + l15; int pc = p > 288 ? 288 : p;
  int oy = pc / 17, ox = pc - oy*17;
  f32x4 acc = {0.f, 0.f, 0.f, 0.f};
  #pragma unroll
  for (int ks = 0; ks < 18; ks++){
    const int tap = ks >> 1;
    const int dy = tap / 3, dx = tap - dy*3;
    int pix2 = (oy+dy)*19 + (ox+dx);
    us8 bv = *(const us8*)(sS + pix2*72 + (ks & 1)*32 + q*8);
    us8 av = *(const us8*)(sW + l15*584 + ks*32 + q*8);
    acc = MFMA16(asbf(av), asbf(bv), acc);     // A: m=cout(l15); B: n=pix(l15)
  }
  return acc;
}

// conv1 + BN + SiLU -> bf16 h (pixel-major). grid = 128: [job:1][b:2][m:2][px:2]
__global__ __launch_bounds__(256) void conv1_k(
    const float* __restrict__ p_low,
    const float* __restrict__ wR, const float* __restrict__ b1R,
    const float* __restrict__ gR, const float* __restrict__ beR,
    const float* __restrict__ mR, const float* __restrict__ vR,
    const float* __restrict__ wT, const float* __restrict__ b1T,
    const float* __restrict__ gT, const float* __restrict__ beT,
    const float* __restrict__ mT, const float* __restrict__ vT,
    u16* __restrict__ hR, u16* __restrict__ hT)
{
  __shared__ __attribute__((aligned(16))) u16 sS[25992];
  __shared__ __attribute__((aligned(16))) u16 sW[9344];
  int tid = threadIdx.x;
  int bx = blockIdx.x;
  int job = bx >> 6;
  int b = (bx >> 4) & 3;
  int m0 = ((bx >> 2) & 3) << 4;
  int px = bx & 3;
  int nt0 = px * 5, ntEnd = nt0 + 5 > 19 ? 19 : nt0 + 5;
  const float* w  = job ? wT  : wR;
  const float* b1 = job ? b1T : b1R;
  const float* g  = job ? gT  : gR;
  const float* be = job ? beT : beR;
  const float* mn = job ? mT  : mR;
  const float* vr = job ? vT  : vR;
  u16* out = job ? hT : hR;
  const float* src = p_low + (size_t)b * 18496;

  stage_zero2(sS, tid);
  __syncthreads();
  stage_src_f32T(src, sS, tid);
  stage_w_f32(w, m0, sW, tid);
  __syncthreads();

  int lane = tid & 63, wave = tid >> 6;
  int l15 = lane & 15, q = lane >> 4;
  float scl[4], sft[4];
  #pragma unroll
  for (int e = 0; e < 4; e++){
    int co = m0 + q*4 + e;
    float s = g[co] / sqrtf(vr[co] + 1e-5f);
    scl[e] = s;
    sft[e] = (b1[co] - mn[co]) * s + be[co];
  }
  for (int nt = nt0 + wave; nt < ntEnd; nt += 4){
    f32x4 acc = conv_tile2(sS, sW, nt, l15, q);
    int p = nt*16 + l15;
    if (p < 289){
      float si[4];
      #pragma unroll
      for (int e = 0; e < 4; e++){
        float y = acc[e]*scl[e] + sft[e];
        si[e] = y / (1.f + __expf(-y));      // SiLU
      }
      uint2 pk;
      pk.x = (uint)f2bf(si[0]) | ((uint)f2bf(si[1]) << 16);
      pk.y = (uint)f2bf(si[2]) | ((uint)f2bf(si[3]) << 16);
      *(uint2*)(out + ((size_t)b*289 + p)*64 + m0 + q*4) = pk;
    }
  }
}

// conv2 (+bias): r-branch -> rlq bf16 [b][pix][1024] pre-scaled by
//   0.125*log2(e); t-branch -> tlq f32 [b][pix][48].
// grid = 268: r: 4b x 64m = 256;  t: 4b x 3m = 12.
__global__ __launch_bounds__(256) void conv2_k(
    const u16* __restrict__ hR, const u16* __restrict__ hT,
    const float* __restrict__ w2R, const float* __restrict__ b2R,
    const float* __restrict__ w2T, const float* __restrict__ b2T,
    u16* __restrict__ rlq, float* __restrict__ tlq)
{
  __shared__ __attribute__((aligned(16))) u16 sS[25992];
  __shared__ __attribute__((aligned(16))) u16 sW[9344];
  int tid = threadIdx.x;
  int bx = blockIdx.x;
  const float *w, *bias; const u16* src;
  int b, m0, isR;
  if (bx < 256){
    isR = 1; b = bx >> 6; m0 = (bx & 63) << 4;
    src = hR + (size_t)b*18496; w = w2R; bias = b2R;
  } else {
    isR = 0; int i = bx - 256; b = i / 3; m0 = (i - b*3) << 4;
    src = hT + (size_t)b*18496; w = w2T; bias = b2T;
  }

  stage_zero2(sS, tid);
  __syncthreads();
  stage_src_pm(src, sS, tid);
  stage_w_f32(w, m0, sW, tid);
  __syncthreads();

  int lane = tid & 63, wave = tid >> 6;
  int l15 = lane & 15, q = lane >> 4;
  float bs[4];
  #pragma unroll
  for (int e = 0; e < 4; e++) bs[e] = bias[m0 + q*4 + e];
  const float PSC = 0.18033688f;   // 0.125 * log2(e)
  for (int nt = wave; nt < 19; nt += 4){
    f32x4 acc = conv_tile2(sS, sW, nt, l15, q);
    int p = nt*16 + l15;
    if (p < 289){
      if (isR){
        uint2 pk;
        pk.x = (uint)f2bf((acc[0]+bs[0])*PSC)
             | ((uint)f2bf((acc[1]+bs[1])*PSC) << 16);
        pk.y = (uint)f2bf((acc[2]+bs[2])*PSC)
             | ((uint)f2bf((acc[3]+bs[3])*PSC) << 16);
        *(uint2*)(rlq + ((size_t)b*289 + p)*1024 + m0 + q*4) = pk;
      } else {
        f32x4 ov = {acc[0]+bs[0], acc[1]+bs[1], acc[2]+bs[2], acc[3]+bs[3]};
        *(f32x4*)(tlq + ((size_t)b*289 + p)*48 + m0 + q*4) = ov;
      }
    }
  }
}

// ---------------------------------------------------------------------------
// Attention: block per (b, tx, ty). Swapped-operand QK^T:
//   score[key = nt*16 + q*4 + e][pixel = l15]; PV lane-local, reduce over q.
// 2-deep register prefetch pipeline, PINNED with sched_barrier(0): the
// compiler's register-minimizing scheduler sank the prefetch loads to
// right before use (R4: VGPR=68, ~1 load in flight, 1.39 TB/s, 17% peak).
// The barrier after the issue block forbids sinking the 16 loads below
// the MFMA/PV compute, forcing a true 2-phase-ahead issue (~32 loads in
// flight per wave). WAR dep (perms read the regs loads overwrite) keeps
// perms above the loads naturally.
// ---------------------------------------------------------------------------
__global__ __launch_bounds__(256) void attn_k(
    const uint* __restrict__ feat,
    const u16* __restrict__ rlq, const float* __restrict__ tlq,
    float* __restrict__ out)
{
  __shared__ __attribute__((aligned(16))) u16 rkT[4608]; // [key=64][72]
  __shared__ __attribute__((aligned(16))) float tkF[256]; // [c=4][key=64]
  int tid = threadIdx.x;
  int ty = blockIdx.x, tx = blockIdx.y, b = blockIdx.z;
  int lane = tid & 63, wave = tid >> 6;
  int l15 = lane & 15, q = lane >> 4;

  { // rk: wave = corner; thread covers couts (lane*16..+16)
    int corner = wave;
    int pix = (tx + (corner >> 1))*17 + ty + (corner & 1);
    const u16* sp = rlq + ((size_t)b*289 + pix)*1024 + lane*16;
    U8u v0, v1; v0.s = *(const us8*)sp; v1.s = *(const us8*)(sp + 8);
    #pragma unroll
    for (int nl = 0; nl < 8; nl++){
      rkT[(corner*16 + nl)*72 + lane]     = v0.u[nl];
      rkT[(corner*16 + 8 + nl)*72 + lane] = v1.u[nl];
    }
  }
  if (tid < 192){
    int corner = tid / 48; int idx = tid - corner*48;
    int pix = (tx + (corner >> 1))*17 + ty + (corner & 1);
    int c = idx >> 4, nl = idx & 15;
    tkF[c*64 + corner*16 + nl] = tlq[((size_t)b*289 + pix)*48 + idx];
  }
  __syncthreads();

  bf16x8 frk[4][2];
  #pragma unroll
  for (int nt = 0; nt < 4; nt++)
    #pragma unroll
    for (int ks = 0; ks < 2; ks++)
      frk[nt][ks] = __builtin_bit_cast(bf16x8,
          *(const us8*)(rkT + (nt*16 + l15)*72 + ks*32 + q*8));

  // per-lane tk base (LDS-resident weights; imm offsets per (c,nt))
  const float* __restrict__ tkq = tkF + q*4;

  const size_t HW = (size_t)512*512;
  // per-lane flat base: channel part (q*8), row base, col
  const uint* fb = feat + ((size_t)b*64 + q*8)*HW
                 + (size_t)(tx*32 + wave*8)*512 + (ty*32 + l15);

  // offsets within a row-tile: cnk -> (row = cnk>>1, col half = cnk&1)
  #define CNK_OFF(c_) ((size_t)((c_) >> 1)*512 + (size_t)(((c_) & 1) << 4))

  uint rA0[8], rA1[8], rB0[8], rB1[8];
  #pragma unroll
  for (int j = 0; j < 8; j++){
    rA0[j] = fb[(size_t)j*HW + CNK_OFF(0)];
    rA1[j] = fb[(size_t)(j+32)*HW + CNK_OFF(0)];
  }
  #pragma unroll
  for (int j = 0; j < 8; j++){
    rB0[j] = fb[(size_t)j*HW + CNK_OFF(1)];
    rB1[j] = fb[(size_t)(j+32)*HW + CNK_OFF(1)];
  }

  #pragma unroll
  for (int cnk = 0; cnk < 16; cnk++){
    uint* r0 = (cnk & 1) ? rB0 : rA0;   // compile-time after full unroll
    uint* r1 = (cnk & 1) ? rB1 : rA1;

    u32x4 p0v, p1v;
    #pragma unroll
    for (int j2 = 0; j2 < 4; j2++){
      p0v[j2] = __builtin_amdgcn_perm(r0[2*j2+1], r0[2*j2], 0x07060302u);
      p1v[j2] = __builtin_amdgcn_perm(r1[2*j2+1], r1[2*j2], 0x07060302u);
    }
    bf16x8 A0 = __builtin_bit_cast(bf16x8, p0v);  // ch  0..31, pixel l15
    bf16x8 A1 = __builtin_bit_cast(bf16x8, p1v);  // ch 32..63

    if (cnk < 14){                                 // issue cnk+2 into freed buf
      #pragma unroll
      for (int j = 0; j < 8; j++){
        r0[j] = fb[(size_t)j*HW + CNK_OFF(cnk + 2)];
        r1[j] = fb[(size_t)(j+32)*HW + CNK_OFF(cnk + 2)];
      }
    }
    // Pin: prefetch loads must be ISSUED before any of the compute below
    // is scheduled; their results stay live across MFMA+PV (2 phases).
    __builtin_amdgcn_sched_barrier(0);

    f32x4 acc[4];
    __builtin_amdgcn_s_setprio(1);
    #pragma unroll
    for (int nt = 0; nt < 4; nt++){
      f32x4 zz = {0.f, 0.f, 0.f, 0.f};
      zz = MFMA16(frk[nt][0], A0, zz);   // A = keys, B = feature
      zz = MFMA16(frk[nt][1], A1, zz);
      acc[nt] = zz;
    }
    __builtin_amdgcn_s_setprio(0);

    // lane-local PV: p = exp2(score), o[c] += p*tk, den += p
    f32x2 den2 = {0.f,0.f}, o0v = {0.f,0.f}, o1v = {0.f,0.f}, o2v = {0.f,0.f};
    #pragma unroll
    for (int nt = 0; nt < 4; nt++){
      f32x4 t0 = *(const f32x4*)(tkq + 0*64 + nt*16);   // ds_read_b128 + imm
      f32x4 t1 = *(const f32x4*)(tkq + 1*64 + nt*16);
      f32x4 t2 = *(const f32x4*)(tkq + 2*64 + nt*16);
      f32x2 pa, pb;
      pa[0] = __builtin_amdgcn_exp2f(acc[nt][0]);
      pa[1] = __builtin_amdgcn_exp2f(acc[nt][1]);
      pb[0] = __builtin_amdgcn_exp2f(acc[nt][2]);
      pb[1] = __builtin_amdgcn_exp2f(acc[nt][3]);
      den2 += pa; den2 += pb;
      f32x2 t0a = {t0[0], t0[1]}, t0b = {t0[2], t0[3]};
      f32x2 t1a = {t1[0], t1[1]}, t1b = {t1[2], t1[3]};
      f32x2 t2a = {t2[0], t2[1]}, t2b = {t2[2], t2[3]};
      o0v = __builtin_elementwise_fma(pa, t0a, o0v);
      o0v = __builtin_elementwise_fma(pb, t0b, o0v);
      o1v = __builtin_elementwise_fma(pa, t1a, o1v);
      o1v = __builtin_elementwise_fma(pb, t1b, o1v);
      o2v = __builtin_elementwise_fma(pa, t2a, o2v);
      o2v = __builtin_elementwise_fma(pb, t2b, o2v);
    }
    float den = den2[0] + den2[1];
    float o0 = o0v[0] + o0v[1];
    float o1 = o1v[0] + o1v[1];
    float o2 = o2v[0] + o2v[1];
    // reduce over the 4 q-groups: xor 16, xor 32
    o0  += __shfl_xor(o0, 16, 64);
    o1  += __shfl_xor(o1, 16, 64);
    o2  += __shfl_xor(o2, 16, 64);
    den += __shfl_xor(den, 16, 64);
    o0  += __shfl_xor(o0, 32, 64);
    o1  += __shfl_xor(o1, 32, 64);
    o2  += __shfl_xor(o2, 32, 64);
    den += __shfl_xor(den, 32, 64);
    float rin = __builtin_amdgcn_rcpf(den);
    float val = (q == 0) ? o0 : ((q == 1) ? o1 : o2);
    int hh = tx*32 + wave*8 + (cnk >> 1);
    int j0 = (cnk & 1) << 4;
    if (q < 3)
      out[((size_t)(b*3 + q)*512 + hh)*512 + (ty*32 + j0 + l15)] = val * rin;
  }
  #undef CNK_OFF
}

extern "C" void kernel_launch(void* const* d_in, const int* in_sizes, int n_in,
                              void* d_out, int out_size, void* d_ws, size_t ws_size,
                              hipStream_t stream)
{
  (void)in_sizes; (void)n_in; (void)out_size; (void)ws_size;
  const uint*  feature = (const uint*)d_in[0];
  const float* p_low = (const float*)d_in[1];
  const float* r_w1 = (const float*)d_in[2];
  const float* r_b1 = (const float*)d_in[3];
  const float* r_g  = (const float*)d_in[4];
  const float* r_be = (const float*)d_in[5];
  const float* r_m  = (const float*)d_in[6];
  const float* r_v  = (const float*)d_in[7];
  const float* r_w2 = (const float*)d_in[8];
  const float* r_b2 = (const float*)d_in[9];
  const float* t_w1 = (const float*)d_in[10];
  const float* t_b1 = (const float*)d_in[11];
  const float* t_g  = (const float*)d_in[12];
  const float* t_be = (const float*)d_in[13];
  const float* t_m  = (const float*)d_in[14];
  const float* t_v  = (const float*)d_in[15];
  const float* t_w2 = (const float*)d_in[16];
  const float* t_b2 = (const float*)d_in[17];

  char* ws = (char*)d_ws;
  u16* hR = (u16*)ws;                          // [4][289][64] bf16 (pixel-major)
  u16* hT = hR + (size_t)4*289*64;             // [4][289][64] bf16 (pixel-major)
  u16* rlq = (u16*)(ws + 295936);              // [4][289][1024] bf16 (x0.125*log2e)
  float* tlq = (float*)(ws + 295936 + 2367488);// [4][289][48] f32
  float* outp = (float*)d_out;

  hipLaunchKernelGGL(conv1_k, dim3(128), dim3(256), 0, stream,
      p_low, r_w1, r_b1, r_g, r_be, r_m, r_v,
      t_w1, t_b1, t_g, t_be, t_m, t_v, hR, hT);
  hipLaunchKernelGGL(conv2_k, dim3(268), dim3(256), 0, stream,
      hR, hT, r_w2, r_b2, t_w2, t_b2, rlq, tlq);
  hipLaunchKernelGGL(attn_k, dim3(16, 16, 4), dim3(256), 0, stream,
      feature, rlq, tlq, outp);
}

// Round 6
// 442.019 us; speedup vs baseline: 1.0084x; 1.0084x over previous
//
#include <hip/hip_runtime.h>

typedef unsigned short u16;
typedef __bf16 bf16x8 __attribute__((ext_vector_type(8)));
typedef unsigned short us8 __attribute__((ext_vector_type(8)));
typedef float f32x4 __attribute__((ext_vector_type(4)));
typedef float f32x2 __attribute__((ext_vector_type(2)));
typedef unsigned int u32x4 __attribute__((ext_vector_type(4)));

union U8u { us8 s; u16 u[8]; };

__device__ __forceinline__ u16 f2bf(float f){
  unsigned u = __builtin_bit_cast(unsigned, f);
  u += 0x7fffu + ((u >> 16) & 1u);
  return (u16)(u >> 16);
}
__device__ __forceinline__ bf16x8 asbf(us8 x){ return __builtin_bit_cast(bf16x8, x); }

#define MFMA16(a,b,c) __builtin_amdgcn_mfma_f32_16x16x32_bf16((a),(b),(c),0,0,0)

// ---------------------------------------------------------------------------
// Conv: 3x3 SAME on 17x17, Cin=64, im2col GEMM, K' = tap*64 + cin.
// LDS sS: PIXEL-major zero-padded [19*19][72] bf16; sW: [cout 16][584] bf16.
// h workspace is PIXEL-major [b][pix][64] so conv2 staging is a straight copy.
// ---------------------------------------------------------------------------
__device__ __forceinline__ void stage_zero2(u16* sS, int tid){
  uint* z = (uint*)sS;
  for (int i = tid; i < 12996; i += 256) z[i] = 0u;   // 361*72 u16
}

__device__ __forceinline__ void stage_src_f32T(const float* __restrict__ src,
                                               u16* sS, int tid){
  for (int i4 = tid; i4 < 4624; i4 += 256){           // 64*289/4
    int e = i4 * 4;
    f32x4 dv = *(const f32x4*)(src + e);
    #pragma unroll
    for (int t = 0; t < 4; t++){
      int ee = e + t;
      int ci = ee / 289; int rr = ee - ci*289;
      int oy = rr / 17;  int ox = rr - oy*17;
      sS[((oy+1)*19 + ox+1)*72 + ci] = f2bf(dv[t]);
    }
  }
}

// pixel-major bf16 source [pix][64] -> one us8 load + one ds_write_b128 per 8
__device__ __forceinline__ void stage_src_pm(const u16* __restrict__ src,
                                             u16* sS, int tid){
  for (int i8 = tid; i8 < 2312; i8 += 256){           // 289*64/8
    int pix = i8 >> 3, c0 = (i8 & 7) << 3;
    us8 v = *(const us8*)(src + ((size_t)pix << 6) + c0);
    int oy = pix / 17, ox = pix - oy*17;
    *(us8*)(sS + ((oy+1)*19 + ox+1)*72 + c0) = v;
  }
}

__device__ __forceinline__ void stage_w_f32(const float* __restrict__ w, int m0,
                                            u16* sW, int tid){
  for (int i4 = tid; i4 < 2304; i4 += 256){           // 16*576/4
    int e = i4 * 4;
    int co = e / 576; int r0 = e - co*576;
    f32x4 wv = *(const f32x4*)(w + (size_t)(m0+co)*576 + r0);
    #pragma unroll
    for (int t = 0; t < 4; t++){
      int r = r0 + t; int cin = r / 9; int tap = r - cin*9;
      sW[co*584 + tap*64 + cin] = f2bf(wv[t]);
    }
  }
}

__device__ __forceinline__ f32x4 conv_tile2(const u16* sS, const u16* sW,
                                            int nt, int l15, int q)
{
  int p = nt*16 + l15; int pc = p > 288 ? 288 : p;
  int oy = pc / 17, ox = pc - oy*17;
  f32x4 acc = {0.f, 0.f, 0.f, 0.f};
  #pragma unroll
  for (int ks = 0; ks < 18; ks++){
    const int tap = ks >> 1;
    const int dy = tap / 3, dx = tap - dy*3;
    int pix2 = (oy+dy)*19 + (ox+dx);
    us8 bv = *(const us8*)(sS + pix2*72 + (ks & 1)*32 + q*8);
    us8 av = *(const us8*)(sW + l15*584 + ks*32 + q*8);
    acc = MFMA16(asbf(av), asbf(bv), acc);     // A: m=cout(l15); B: n=pix(l15)
  }
  return acc;
}

// conv1 + BN + SiLU -> bf16 h (pixel-major). grid = 128: [job:1][b:2][m:2][px:2]
__global__ __launch_bounds__(256) void conv1_k(
    const float* __restrict__ p_low,
    const float* __restrict__ wR, const float* __restrict__ b1R,
    const float* __restrict__ gR, const float* __restrict__ beR,
    const float* __restrict__ mR, const float* __restrict__ vR,
    const float* __restrict__ wT, const float* __restrict__ b1T,
    const float* __restrict__ gT, const float* __restrict__ beT,
    const float* __restrict__ mT, const float* __restrict__ vT,
    u16* __restrict__ hR, u16* __restrict__ hT)
{
  __shared__ __attribute__((aligned(16))) u16 sS[25992];
  __shared__ __attribute__((aligned(16))) u16 sW[9344];
  int tid = threadIdx.x;
  int bx = blockIdx.x;
  int job = bx >> 6;
  int b = (bx >> 4) & 3;
  int m0 = ((bx >> 2) & 3) << 4;
  int px = bx & 3;
  int nt0 = px * 5, ntEnd = nt0 + 5 > 19 ? 19 : nt0 + 5;
  const float* w  = job ? wT  : wR;
  const float* b1 = job ? b1T : b1R;
  const float* g  = job ? gT  : gR;
  const float* be = job ? beT : beR;
  const float* mn = job ? mT  : mR;
  const float* vr = job ? vT  : vR;
  u16* out = job ? hT : hR;
  const float* src = p_low + (size_t)b * 18496;

  stage_zero2(sS, tid);
  __syncthreads();
  stage_src_f32T(src, sS, tid);
  stage_w_f32(w, m0, sW, tid);
  __syncthreads();

  int lane = tid & 63, wave = tid >> 6;
  int l15 = lane & 15, q = lane >> 4;
  float scl[4], sft[4];
  #pragma unroll
  for (int e = 0; e < 4; e++){
    int co = m0 + q*4 + e;
    float s = g[co] / sqrtf(vr[co] + 1e-5f);
    scl[e] = s;
    sft[e] = (b1[co] - mn[co]) * s + be[co];
  }
  for (int nt = nt0 + wave; nt < ntEnd; nt += 4){
    f32x4 acc = conv_tile2(sS, sW, nt, l15, q);
    int p = nt*16 + l15;
    if (p < 289){
      float si[4];
      #pragma unroll
      for (int e = 0; e < 4; e++){
        float y = acc[e]*scl[e] + sft[e];
        si[e] = y / (1.f + __expf(-y));      // SiLU
      }
      uint2 pk;
      pk.x = (uint)f2bf(si[0]) | ((uint)f2bf(si[1]) << 16);
      pk.y = (uint)f2bf(si[2]) | ((uint)f2bf(si[3]) << 16);
      *(uint2*)(out + ((size_t)b*289 + p)*64 + m0 + q*4) = pk;
    }
  }
}

// conv2 (+bias): r-branch -> rlq bf16 [b][pix][1024] pre-scaled by
//   0.125*log2(e); t-branch -> tlq f32 [b][pix][48].
// grid = 268: r: 4b x 64m = 256;  t: 4b x 3m = 12.
__global__ __launch_bounds__(256) void conv2_k(
    const u16* __restrict__ hR, const u16* __restrict__ hT,
    const float* __restrict__ w2R, const float* __restrict__ b2R,
    const float* __restrict__ w2T, const float* __restrict__ b2T,
    u16* __restrict__ rlq, float* __restrict__ tlq)
{
  __shared__ __attribute__((aligned(16))) u16 sS[25992];
  __shared__ __attribute__((aligned(16))) u16 sW[9344];
  int tid = threadIdx.x;
  int bx = blockIdx.x;
  const float *w, *bias; const u16* src;
  int b, m0, isR;
  if (bx < 256){
    isR = 1; b = bx >> 6; m0 = (bx & 63) << 4;
    src = hR + (size_t)b*18496; w = w2R; bias = b2R;
  } else {
    isR = 0; int i = bx - 256; b = i / 3; m0 = (i - b*3) << 4;
    src = hT + (size_t)b*18496; w = w2T; bias = b2T;
  }

  stage_zero2(sS, tid);
  __syncthreads();
  stage_src_pm(src, sS, tid);
  stage_w_f32(w, m0, sW, tid);
  __syncthreads();

  int lane = tid & 63, wave = tid >> 6;
  int l15 = lane & 15, q = lane >> 4;
  float bs[4];
  #pragma unroll
  for (int e = 0; e < 4; e++) bs[e] = bias[m0 + q*4 + e];
  const float PSC = 0.18033688f;   // 0.125 * log2(e)
  for (int nt = wave; nt < 19; nt += 4){
    f32x4 acc = conv_tile2(sS, sW, nt, l15, q);
    int p = nt*16 + l15;
    if (p < 289){
      if (isR){
        uint2 pk;
        pk.x = (uint)f2bf((acc[0]+bs[0])*PSC)
             | ((uint)f2bf((acc[1]+bs[1])*PSC) << 16);
        pk.y = (uint)f2bf((acc[2]+bs[2])*PSC)
             | ((uint)f2bf((acc[3]+bs[3])*PSC) << 16);
        *(uint2*)(rlq + ((size_t)b*289 + p)*1024 + m0 + q*4) = pk;
      } else {
        f32x4 ov = {acc[0]+bs[0], acc[1]+bs[1], acc[2]+bs[2], acc[3]+bs[3]};
        *(f32x4*)(tlq + ((size_t)b*289 + p)*48 + m0 + q*4) = ov;
      }
    }
  }
}

// ---------------------------------------------------------------------------
// Attention v2: block per (b, tx, ty). Feature tile (64ch x 32x32 px, 256 KB)
// staged through LDS in 8 chunks of 4 rows (rows {i*8+c}, i=0..3):
//   - global_load_lds width=16: each wave covers 8 full 128-B row segments
//     per instruction (fully coalesced); LDS dest linear (base + lane*16).
//   - LDS layout sF[i=4][ch=64][col=32] f32 with col XOR-swizzled by (q<<3):
//     source col pre-swizzled on the WRITE (per-lane global addr), same XOR
//     on the READ => 2 lanes/bank (free). Rule #21: both-sides-or-neither.
//   - read side: 16 ds_read_b32 (ch-major, ds_read2-fusable) + perm-truncate
//     => bit-identical A fragments to the previous gather path.
// Compute (swapped-operand QK^T, lane-local PV, q-group reduce) unchanged.
// 3 blocks/CU (43 KB LDS); staging of one block hides under the other two.
// ---------------------------------------------------------------------------
__global__ __launch_bounds__(256) void attn_k(
    const uint* __restrict__ feat,
    const u16* __restrict__ rlq, const float* __restrict__ tlq,
    float* __restrict__ out)
{
  __shared__ __attribute__((aligned(16))) u16 rkT[4608];  // [key=64][72]
  __shared__ __attribute__((aligned(16))) float tkF[256]; // [c=4][key=64]
  __shared__ __attribute__((aligned(1024))) uint sF[8192];// [i4][ch64][col32] f32
  int tid = threadIdx.x;
  int ty = blockIdx.x, tx = blockIdx.y, b = blockIdx.z;
  int lane = tid & 63, wave = tid >> 6;
  int l15 = lane & 15, q = lane >> 4;

  { // rk: wave = corner; thread covers couts (lane*16..+16)
    int corner = wave;
    int pix = (tx + (corner >> 1))*17 + ty + (corner & 1);
    const u16* sp = rlq + ((size_t)b*289 + pix)*1024 + lane*16;
    U8u v0, v1; v0.s = *(const us8*)sp; v1.s = *(const us8*)(sp + 8);
    #pragma unroll
    for (int nl = 0; nl < 8; nl++){
      rkT[(corner*16 + nl)*72 + lane]     = v0.u[nl];
      rkT[(corner*16 + 8 + nl)*72 + lane] = v1.u[nl];
    }
  }
  if (tid < 192){
    int corner = tid / 48; int idx = tid - corner*48;
    int pix = (tx + (corner >> 1))*17 + ty + (corner & 1);
    int c = idx >> 4, nl = idx & 15;
    tkF[c*64 + corner*16 + nl] = tlq[((size_t)b*289 + pix)*48 + idx];
  }
  __syncthreads();

  bf16x8 frk[4][2];
  #pragma unroll
  for (int nt = 0; nt < 4; nt++)
    #pragma unroll
    for (int ks = 0; ks < 2; ks++)
      frk[nt][ks] = __builtin_bit_cast(bf16x8,
          *(const us8*)(rkT + (nt*16 + l15)*72 + ks*32 + q*8));

  // per-lane tk base (LDS-resident weights; imm offsets per (c,nt))
  const float* __restrict__ tkq = tkF + q*4;

  const size_t HW = (size_t)512*512;
  // staging lane constants: seg = p*32 + segl covers (i = seg>>6, ch = seg&63)
  int segl = (wave << 3) + (lane >> 3);
  int part = lane & 7;

  for (int c = 0; c < 8; ++c){
    // ---- stage chunk c: rows {i*8 + c} ----
    #pragma unroll
    for (int p = 0; p < 8; ++p){
      int seg = p*32 + segl;
      int i  = seg >> 6;
      int ch = seg & 63;
      int qq = (ch >> 3) & 3;
      int col0 = ((part ^ (qq << 1)) << 2);    // source pre-swizzle (XOR q<<3 on col)
      const uint* src = feat + ((size_t)(b*64 + ch))*HW
                      + (size_t)(tx*32 + i*8 + c)*512 + (ty*32 + col0);
      uint* dst = sF + (size_t)(p*32 + (wave << 3))*32;   // wave-uniform base
      __builtin_amdgcn_global_load_lds(
          (const __attribute__((address_space(1))) void*)src,
          (__attribute__((address_space(3))) void*)dst, 16, 0, 0);
    }
    __syncthreads();   // drains vmcnt -> chunk resident

    // ---- compute: wave w owns row i=w of the chunk; 2 col-halves ----
    #pragma unroll
    for (int h = 0; h < 2; ++h){
      int colL = ((h << 4) + l15) ^ (q << 3);  // same XOR as the write side
      const uint* fp = sF + wave*2048 + q*256 + colL;
      uint r0[8], r1[8];
      #pragma unroll
      for (int j = 0; j < 8; j++){
        r0[j] = fp[j*32];          // ch q*8+j   (f32 bits)
        r1[j] = fp[1024 + j*32];   // ch 32+q*8+j
      }
      u32x4 p0v, p1v;
      #pragma unroll
      for (int j2 = 0; j2 < 4; j2++){
        p0v[j2] = __builtin_amdgcn_perm(r0[2*j2+1], r0[2*j2], 0x07060302u);
        p1v[j2] = __builtin_amdgcn_perm(r1[2*j2+1], r1[2*j2], 0x07060302u);
      }
      bf16x8 A0 = __builtin_bit_cast(bf16x8, p0v);  // ch  0..31, pixel l15
      bf16x8 A1 = __builtin_bit_cast(bf16x8, p1v);  // ch 32..63

      f32x4 acc[4];
      #pragma unroll
      for (int nt = 0; nt < 4; nt++){
        f32x4 zz = {0.f, 0.f, 0.f, 0.f};
        zz = MFMA16(frk[nt][0], A0, zz);   // A = keys, B = feature
        zz = MFMA16(frk[nt][1], A1, zz);
        acc[nt] = zz;
      }

      // lane-local PV: p = exp2(score), o[c] += p*tk, den += p
      f32x2 den2 = {0.f,0.f}, o0v = {0.f,0.f}, o1v = {0.f,0.f}, o2v = {0.f,0.f};
      #pragma unroll
      for (int nt = 0; nt < 4; nt++){
        f32x4 t0 = *(const f32x4*)(tkq + 0*64 + nt*16);   // ds_read_b128 + imm
        f32x4 t1 = *(const f32x4*)(tkq + 1*64 + nt*16);
        f32x4 t2 = *(const f32x4*)(tkq + 2*64 + nt*16);
        f32x2 pa, pb;
        pa[0] = __builtin_amdgcn_exp2f(acc[nt][0]);
        pa[1] = __builtin_amdgcn_exp2f(acc[nt][1]);
        pb[0] = __builtin_amdgcn_exp2f(acc[nt][2]);
        pb[1] = __builtin_amdgcn_exp2f(acc[nt][3]);
        den2 += pa; den2 += pb;
        f32x2 t0a = {t0[0], t0[1]}, t0b = {t0[2], t0[3]};
        f32x2 t1a = {t1[0], t1[1]}, t1b = {t1[2], t1[3]};
        f32x2 t2a = {t2[0], t2[1]}, t2b = {t2[2], t2[3]};
        o0v = __builtin_elementwise_fma(pa, t0a, o0v);
        o0v = __builtin_elementwise_fma(pb, t0b, o0v);
        o1v = __builtin_elementwise_fma(pa, t1a, o1v);
        o1v = __builtin_elementwise_fma(pb, t1b, o1v);
        o2v = __builtin_elementwise_fma(pa, t2a, o2v);
        o2v = __builtin_elementwise_fma(pb, t2b, o2v);
      }
      float den = den2[0] + den2[1];
      float o0 = o0v[0] + o0v[1];
      float o1 = o1v[0] + o1v[1];
      float o2 = o2v[0] + o2v[1];
      // reduce over the 4 q-groups: xor 16, xor 32
      o0  += __shfl_xor(o0, 16, 64);
      o1  += __shfl_xor(o1, 16, 64);
      o2  += __shfl_xor(o2, 16, 64);
      den += __shfl_xor(den, 16, 64);
      o0  += __shfl_xor(o0, 32, 64);
      o1  += __shfl_xor(o1, 32, 64);
      o2  += __shfl_xor(o2, 32, 64);
      den += __shfl_xor(den, 32, 64);
      float rin = __builtin_amdgcn_rcpf(den);
      float val = (q == 0) ? o0 : ((q == 1) ? o1 : o2);
      int hh = tx*32 + wave*8 + c;
      int j0 = h << 4;
      if (q < 3)
        out[((size_t)(b*3 + q)*512 + hh)*512 + (ty*32 + j0 + l15)] = val * rin;
    }
    __syncthreads();   // compute done -> safe to overwrite sF next chunk
  }
}

extern "C" void kernel_launch(void* const* d_in, const int* in_sizes, int n_in,
                              void* d_out, int out_size, void* d_ws, size_t ws_size,
                              hipStream_t stream)
{
  (void)in_sizes; (void)n_in; (void)out_size; (void)ws_size;
  const uint*  feature = (const uint*)d_in[0];
  const float* p_low = (const float*)d_in[1];
  const float* r_w1 = (const float*)d_in[2];
  const float* r_b1 = (const float*)d_in[3];
  const float* r_g  = (const float*)d_in[4];
  const float* r_be = (const float*)d_in[5];
  const float* r_m  = (const float*)d_in[6];
  const float* r_v  = (const float*)d_in[7];
  const float* r_w2 = (const float*)d_in[8];
  const float* r_b2 = (const float*)d_in[9];
  const float* t_w1 = (const float*)d_in[10];
  const float* t_b1 = (const float*)d_in[11];
  const float* t_g  = (const float*)d_in[12];
  const float* t_be = (const float*)d_in[13];
  const float* t_m  = (const float*)d_in[14];
  const float* t_v  = (const float*)d_in[15];
  const float* t_w2 = (const float*)d_in[16];
  const float* t_b2 = (const float*)d_in[17];

  char* ws = (char*)d_ws;
  u16* hR = (u16*)ws;                          // [4][289][64] bf16 (pixel-major)
  u16* hT = hR + (size_t)4*289*64;             // [4][289][64] bf16 (pixel-major)
  u16* rlq = (u16*)(ws + 295936);              // [4][289][1024] bf16 (x0.125*log2e)
  float* tlq = (float*)(ws + 295936 + 2367488);// [4][289][48] f32
  float* outp = (float*)d_out;

  hipLaunchKernelGGL(conv1_k, dim3(128), dim3(256), 0, stream,
      p_low, r_w1, r_b1, r_g, r_be, r_m, r_v,
      t_w1, t_b1, t_g, t_be, t_m, t_v, hR, hT);
  hipLaunchKernelGGL(conv2_k, dim3(268), dim3(256), 0, stream,
      hR, hT, r_w2, r_b2, t_w2, t_b2, rlq, tlq);
  hipLaunchKernelGGL(attn_k, dim3(16, 16, 4), dim3(256), 0, stream,
      feature, rlq, tlq, outp);
}

// Round 7
// 436.532 us; speedup vs baseline: 1.0211x; 1.0126x over previous
//
#include <hip/hip_runtime.h>

typedef unsigned short u16;
typedef __bf16 bf16x8 __attribute__((ext_vector_type(8)));
typedef unsigned short us8 __attribute__((ext_vector_type(8)));
typedef float f32x4 __attribute__((ext_vector_type(4)));
typedef float f32x2 __attribute__((ext_vector_type(2)));
typedef unsigned int u32x4 __attribute__((ext_vector_type(4)));

union U8u { us8 s; u16 u[8]; };

__device__ __forceinline__ u16 f2bf(float f){
  unsigned u = __builtin_bit_cast(unsigned, f);
  u += 0x7fffu + ((u >> 16) & 1u);
  return (u16)(u >> 16);
}
__device__ __forceinline__ bf16x8 asbf(us8 x){ return __builtin_bit_cast(bf16x8, x); }

#define MFMA16(a,b,c) __builtin_amdgcn_mfma_f32_16x16x32_bf16((a),(b),(c),0,0,0)

// ---------------------------------------------------------------------------
// Conv: 3x3 SAME on 17x17, Cin=64, im2col GEMM, K' = tap*64 + cin.
// LDS sS: PIXEL-major zero-padded [19*19][72] bf16; sW: [cout 16][584] bf16.
// h workspace is PIXEL-major [b][pix][64] so conv2 staging is a straight copy.
// ---------------------------------------------------------------------------
__device__ __forceinline__ void stage_zero2(u16* sS, int tid){
  uint* z = (uint*)sS;
  for (int i = tid; i < 12996; i += 256) z[i] = 0u;   // 361*72 u16
}

__device__ __forceinline__ void stage_src_f32T(const float* __restrict__ src,
                                               u16* sS, int tid){
  for (int i4 = tid; i4 < 4624; i4 += 256){           // 64*289/4
    int e = i4 * 4;
    f32x4 dv = *(const f32x4*)(src + e);
    #pragma unroll
    for (int t = 0; t < 4; t++){
      int ee = e + t;
      int ci = ee / 289; int rr = ee - ci*289;
      int oy = rr / 17;  int ox = rr - oy*17;
      sS[((oy+1)*19 + ox+1)*72 + ci] = f2bf(dv[t]);
    }
  }
}

// pixel-major bf16 source [pix][64] -> one us8 load + one ds_write_b128 per 8
__device__ __forceinline__ void stage_src_pm(const u16* __restrict__ src,
                                             u16* sS, int tid){
  for (int i8 = tid; i8 < 2312; i8 += 256){           // 289*64/8
    int pix = i8 >> 3, c0 = (i8 & 7) << 3;
    us8 v = *(const us8*)(src + ((size_t)pix << 6) + c0);
    int oy = pix / 17, ox = pix - oy*17;
    *(us8*)(sS + ((oy+1)*19 + ox+1)*72 + c0) = v;
  }
}

__device__ __forceinline__ void stage_w_f32(const float* __restrict__ w, int m0,
                                            u16* sW, int tid){
  for (int i4 = tid; i4 < 2304; i4 += 256){           // 16*576/4
    int e = i4 * 4;
    int co = e / 576; int r0 = e - co*576;
    f32x4 wv = *(const f32x4*)(w + (size_t)(m0+co)*576 + r0);
    #pragma unroll
    for (int t = 0; t < 4; t++){
      int r = r0 + t; int cin = r / 9; int tap = r - cin*9;
      sW[co*584 + tap*64 + cin] = f2bf(wv[t]);
    }
  }
}

__device__ __forceinline__ f32x4 conv_tile2(const u16* sS, const u16* sW,
                                            int nt, int l15, int q)
{
  int p = nt*16 + l15; int pc = p > 288 ? 288 : p;
  int oy = pc / 17, ox = pc - oy*17;
  f32x4 acc = {0.f, 0.f, 0.f, 0.f};
  #pragma unroll
  for (int ks = 0; ks < 18; ks++){
    const int tap = ks >> 1;
    const int dy = tap / 3, dx = tap - dy*3;
    int pix2 = (oy+dy)*19 + (ox+dx);
    us8 bv = *(const us8*)(sS + pix2*72 + (ks & 1)*32 + q*8);
    us8 av = *(const us8*)(sW + l15*584 + ks*32 + q*8);
    acc = MFMA16(asbf(av), asbf(bv), acc);     // A: m=cout(l15); B: n=pix(l15)
  }
  return acc;
}

// conv1 + BN + SiLU -> bf16 h (pixel-major). grid = 128: [job:1][b:2][m:2][px:2]
__global__ __launch_bounds__(256) void conv1_k(
    const float* __restrict__ p_low,
    const float* __restrict__ wR, const float* __restrict__ b1R,
    const float* __restrict__ gR, const float* __restrict__ beR,
    const float* __restrict__ mR, const float* __restrict__ vR,
    const float* __restrict__ wT, const float* __restrict__ b1T,
    const float* __restrict__ gT, const float* __restrict__ beT,
    const float* __restrict__ mT, const float* __restrict__ vT,
    u16* __restrict__ hR, u16* __restrict__ hT)
{
  __shared__ __attribute__((aligned(16))) u16 sS[25992];
  __shared__ __attribute__((aligned(16))) u16 sW[9344];
  int tid = threadIdx.x;
  int bx = blockIdx.x;
  int job = bx >> 6;
  int b = (bx >> 4) & 3;
  int m0 = ((bx >> 2) & 3) << 4;
  int px = bx & 3;
  int nt0 = px * 5, ntEnd = nt0 + 5 > 19 ? 19 : nt0 + 5;
  const float* w  = job ? wT  : wR;
  const float* b1 = job ? b1T : b1R;
  const float* g  = job ? gT  : gR;
  const float* be = job ? beT : beR;
  const float* mn = job ? mT  : mR;
  const float* vr = job ? vT  : vR;
  u16* out = job ? hT : hR;
  const float* src = p_low + (size_t)b * 18496;

  stage_zero2(sS, tid);
  __syncthreads();
  stage_src_f32T(src, sS, tid);
  stage_w_f32(w, m0, sW, tid);
  __syncthreads();

  int lane = tid & 63, wave = tid >> 6;
  int l15 = lane & 15, q = lane >> 4;
  float scl[4], sft[4];
  #pragma unroll
  for (int e = 0; e < 4; e++){
    int co = m0 + q*4 + e;
    float s = g[co] / sqrtf(vr[co] + 1e-5f);
    scl[e] = s;
    sft[e] = (b1[co] - mn[co]) * s + be[co];
  }
  for (int nt = nt0 + wave; nt < ntEnd; nt += 4){
    f32x4 acc = conv_tile2(sS, sW, nt, l15, q);
    int p = nt*16 + l15;
    if (p < 289){
      float si[4];
      #pragma unroll
      for (int e = 0; e < 4; e++){
        float y = acc[e]*scl[e] + sft[e];
        si[e] = y / (1.f + __expf(-y));      // SiLU
      }
      uint2 pk;
      pk.x = (uint)f2bf(si[0]) | ((uint)f2bf(si[1]) << 16);
      pk.y = (uint)f2bf(si[2]) | ((uint)f2bf(si[3]) << 16);
      *(uint2*)(out + ((size_t)b*289 + p)*64 + m0 + q*4) = pk;
    }
  }
}

// conv2 (+bias): r-branch -> rlq bf16 [b][pix][1024] pre-scaled by
//   0.125*log2(e); t-branch -> tlq f32 [b][pix][48].
// grid = 268: r: 4b x 64m = 256;  t: 4b x 3m = 12.
__global__ __launch_bounds__(256) void conv2_k(
    const u16* __restrict__ hR, const u16* __restrict__ hT,
    const float* __restrict__ w2R, const float* __restrict__ b2R,
    const float* __restrict__ w2T, const float* __restrict__ b2T,
    u16* __restrict__ rlq, float* __restrict__ tlq)
{
  __shared__ __attribute__((aligned(16))) u16 sS[25992];
  __shared__ __attribute__((aligned(16))) u16 sW[9344];
  int tid = threadIdx.x;
  int bx = blockIdx.x;
  const float *w, *bias; const u16* src;
  int b, m0, isR;
  if (bx < 256){
    isR = 1; b = bx >> 6; m0 = (bx & 63) << 4;
    src = hR + (size_t)b*18496; w = w2R; bias = b2R;
  } else {
    isR = 0; int i = bx - 256; b = i / 3; m0 = (i - b*3) << 4;
    src = hT + (size_t)b*18496; w = w2T; bias = b2T;
  }

  stage_zero2(sS, tid);
  __syncthreads();
  stage_src_pm(src, sS, tid);
  stage_w_f32(w, m0, sW, tid);
  __syncthreads();

  int lane = tid & 63, wave = tid >> 6;
  int l15 = lane & 15, q = lane >> 4;
  float bs[4];
  #pragma unroll
  for (int e = 0; e < 4; e++) bs[e] = bias[m0 + q*4 + e];
  const float PSC = 0.18033688f;   // 0.125 * log2(e)
  for (int nt = wave; nt < 19; nt += 4){
    f32x4 acc = conv_tile2(sS, sW, nt, l15, q);
    int p = nt*16 + l15;
    if (p < 289){
      if (isR){
        uint2 pk;
        pk.x = (uint)f2bf((acc[0]+bs[0])*PSC)
             | ((uint)f2bf((acc[1]+bs[1])*PSC) << 16);
        pk.y = (uint)f2bf((acc[2]+bs[2])*PSC)
             | ((uint)f2bf((acc[3]+bs[3])*PSC) << 16);
        *(uint2*)(rlq + ((size_t)b*289 + p)*1024 + m0 + q*4) = pk;
      } else {
        f32x4 ov = {acc[0]+bs[0], acc[1]+bs[1], acc[2]+bs[2], acc[3]+bs[3]};
        *(f32x4*)(tlq + ((size_t)b*289 + p)*48 + m0 + q*4) = ov;
      }
    }
  }
}

// ---------------------------------------------------------------------------
// Attention v3: block per (b, tx, ty). Feature tile staged via coalesced
// global_load_lds into a PING-PONG double buffer sF[2][4r][64ch][32col]:
//   chunk loop: {ds_read both col-halves into regs} -> {issue stage(c+1)
//   into other buffer + sched_barrier} -> {register-only compute (tk in
//   VGPRs, no LDS op)} -> __syncthreads (the barrier's vmcnt(0) drain IS
//   the pipeline wait for chunk c+1). HBM issue is continuous per block;
//   2 blocks/CU (74 KB LDS) keep the CU's BW share saturated.
// Col XOR-swizzle (q<<3) applied on BOTH write (pre-swizzled global col)
// and read => 2 lanes/bank. Compute math identical to v2.
// ---------------------------------------------------------------------------
__global__ __launch_bounds__(256) void attn_k(
    const uint* __restrict__ feat,
    const u16* __restrict__ rlq, const float* __restrict__ tlq,
    float* __restrict__ out)
{
  __shared__ __attribute__((aligned(16))) u16 rkT[4608];  // [key=64][72]
  __shared__ __attribute__((aligned(16))) float tkF[256]; // [c=4][key=64]
  __shared__ __attribute__((aligned(1024))) uint sF[2][8192]; // 2x[4][64][32] f32
  int tid = threadIdx.x;
  int ty = blockIdx.x, tx = blockIdx.y, b = blockIdx.z;
  int lane = tid & 63, wave = tid >> 6;
  int l15 = lane & 15, q = lane >> 4;

  { // rk: wave = corner; thread covers couts (lane*16..+16)
    int corner = wave;
    int pix = (tx + (corner >> 1))*17 + ty + (corner & 1);
    const u16* sp = rlq + ((size_t)b*289 + pix)*1024 + lane*16;
    U8u v0, v1; v0.s = *(const us8*)sp; v1.s = *(const us8*)(sp + 8);
    #pragma unroll
    for (int nl = 0; nl < 8; nl++){
      rkT[(corner*16 + nl)*72 + lane]     = v0.u[nl];
      rkT[(corner*16 + 8 + nl)*72 + lane] = v1.u[nl];
    }
  }
  if (tid < 192){
    int corner = tid / 48; int idx = tid - corner*48;
    int pix = (tx + (corner >> 1))*17 + ty + (corner & 1);
    int c = idx >> 4, nl = idx & 15;
    tkF[c*64 + corner*16 + nl] = tlq[((size_t)b*289 + pix)*48 + idx];
  }
  __syncthreads();

  bf16x8 frk[4][2];
  #pragma unroll
  for (int nt = 0; nt < 4; nt++)
    #pragma unroll
    for (int ks = 0; ks < 2; ks++)
      frk[nt][ks] = __builtin_bit_cast(bf16x8,
          *(const us8*)(rkT + (nt*16 + l15)*72 + ks*32 + q*8));

  // tk weights hoisted to registers: NO LDS reads inside the chunk loop's
  // compute, so nothing can force an early vmcnt wait on the prefetch.
  f32x4 tkc[3][4];
  #pragma unroll
  for (int c = 0; c < 3; c++)
    #pragma unroll
    for (int nt = 0; nt < 4; nt++)
      tkc[c][nt] = *(const f32x4*)(tkF + c*64 + nt*16 + q*4);

  const size_t HW = (size_t)512*512;
  // staging lane constants: seg = p*32 + segl covers (i = seg>>6, ch = seg&63)
  int segl = (wave << 3) + (lane >> 3);
  int part = lane & 7;

  #define STAGE(c_, bb_)                                                     \
    _Pragma("unroll")                                                        \
    for (int p = 0; p < 8; ++p){                                             \
      int seg = p*32 + segl;                                                 \
      int i  = seg >> 6;                                                     \
      int ch = seg & 63;                                                     \
      int qq = (ch >> 3) & 3;                                                \
      int col0 = ((part ^ (qq << 1)) << 2);                                  \
      const uint* src = feat + ((size_t)(b*64 + ch))*HW                      \
                      + (size_t)(tx*32 + i*8 + (c_))*512 + (ty*32 + col0);   \
      uint* dst = sF[bb_] + (size_t)(p*32 + (wave << 3))*32;                 \
      __builtin_amdgcn_global_load_lds(                                      \
          (const __attribute__((address_space(1))) void*)src,                \
          (__attribute__((address_space(3))) void*)dst, 16, 0, 0);           \
    }

  STAGE(0, 0);
  __syncthreads();   // chunk 0 resident

  for (int c = 0; c < 8; ++c){
    int bb = c & 1;
    // ---- ds-read both col-halves of this wave's row into registers ----
    uint r0[2][8], r1[2][8];
    #pragma unroll
    for (int h = 0; h < 2; ++h){
      int colL = ((h << 4) + l15) ^ (q << 3);  // same XOR as write side
      const uint* fp = sF[bb] + wave*2048 + q*256 + colL;
      #pragma unroll
      for (int j = 0; j < 8; j++){
        r0[h][j] = fp[j*32];          // ch q*8+j   (f32 bits)
        r1[h][j] = fp[1024 + j*32];   // ch 32+q*8+j
      }
    }
    // ---- issue next chunk into the other buffer; pin issue point ----
    if (c < 7){ STAGE(c+1, bb^1); }
    __builtin_amdgcn_sched_barrier(0);

    // ---- register-only compute for both halves ----
    #pragma unroll
    for (int h = 0; h < 2; ++h){
      u32x4 p0v, p1v;
      #pragma unroll
      for (int j2 = 0; j2 < 4; j2++){
        p0v[j2] = __builtin_amdgcn_perm(r0[h][2*j2+1], r0[h][2*j2], 0x07060302u);
        p1v[j2] = __builtin_amdgcn_perm(r1[h][2*j2+1], r1[h][2*j2], 0x07060302u);
      }
      bf16x8 A0 = __builtin_bit_cast(bf16x8, p0v);  // ch  0..31, pixel l15
      bf16x8 A1 = __builtin_bit_cast(bf16x8, p1v);  // ch 32..63

      f32x4 acc[4];
      #pragma unroll
      for (int nt = 0; nt < 4; nt++){
        f32x4 zz = {0.f, 0.f, 0.f, 0.f};
        zz = MFMA16(frk[nt][0], A0, zz);   // A = keys, B = feature
        zz = MFMA16(frk[nt][1], A1, zz);
        acc[nt] = zz;
      }

      // lane-local PV: p = exp2(score), o[c] += p*tk, den += p
      f32x2 den2 = {0.f,0.f}, o0v = {0.f,0.f}, o1v = {0.f,0.f}, o2v = {0.f,0.f};
      #pragma unroll
      for (int nt = 0; nt < 4; nt++){
        f32x2 pa, pb;
        pa[0] = __builtin_amdgcn_exp2f(acc[nt][0]);
        pa[1] = __builtin_amdgcn_exp2f(acc[nt][1]);
        pb[0] = __builtin_amdgcn_exp2f(acc[nt][2]);
        pb[1] = __builtin_amdgcn_exp2f(acc[nt][3]);
        den2 += pa; den2 += pb;
        f32x2 t0a = {tkc[0][nt][0], tkc[0][nt][1]};
        f32x2 t0b = {tkc[0][nt][2], tkc[0][nt][3]};
        f32x2 t1a = {tkc[1][nt][0], tkc[1][nt][1]};
        f32x2 t1b = {tkc[1][nt][2], tkc[1][nt][3]};
        f32x2 t2a = {tkc[2][nt][0], tkc[2][nt][1]};
        f32x2 t2b = {tkc[2][nt][2], tkc[2][nt][3]};
        o0v = __builtin_elementwise_fma(pa, t0a, o0v);
        o0v = __builtin_elementwise_fma(pb, t0b, o0v);
        o1v = __builtin_elementwise_fma(pa, t1a, o1v);
        o1v = __builtin_elementwise_fma(pb, t1b, o1v);
        o2v = __builtin_elementwise_fma(pa, t2a, o2v);
        o2v = __builtin_elementwise_fma(pb, t2b, o2v);
      }
      float den = den2[0] + den2[1];
      float o0 = o0v[0] + o0v[1];
      float o1 = o1v[0] + o1v[1];
      float o2 = o2v[0] + o2v[1];
      // reduce over the 4 q-groups: xor 16, xor 32
      o0  += __shfl_xor(o0, 16, 64);
      o1  += __shfl_xor(o1, 16, 64);
      o2  += __shfl_xor(o2, 16, 64);
      den += __shfl_xor(den, 16, 64);
      o0  += __shfl_xor(o0, 32, 64);
      o1  += __shfl_xor(o1, 32, 64);
      o2  += __shfl_xor(o2, 32, 64);
      den += __shfl_xor(den, 32, 64);
      float rin = __builtin_amdgcn_rcpf(den);
      float val = (q == 0) ? o0 : ((q == 1) ? o1 : o2);
      int hh = tx*32 + wave*8 + c;
      int j0 = h << 4;
      if (q < 3)
        out[((size_t)(b*3 + q)*512 + hh)*512 + (ty*32 + j0 + l15)] = val * rin;
    }
    __syncthreads();   // vmcnt(0) drain = wait for chunk c+1; frees buf bb
  }
  #undef STAGE
}

extern "C" void kernel_launch(void* const* d_in, const int* in_sizes, int n_in,
                              void* d_out, int out_size, void* d_ws, size_t ws_size,
                              hipStream_t stream)
{
  (void)in_sizes; (void)n_in; (void)out_size; (void)ws_size;
  const uint*  feature = (const uint*)d_in[0];
  const float* p_low = (const float*)d_in[1];
  const float* r_w1 = (const float*)d_in[2];
  const float* r_b1 = (const float*)d_in[3];
  const float* r_g  = (const float*)d_in[4];
  const float* r_be = (const float*)d_in[5];
  const float* r_m  = (const float*)d_in[6];
  const float* r_v  = (const float*)d_in[7];
  const float* r_w2 = (const float*)d_in[8];
  const float* r_b2 = (const float*)d_in[9];
  const float* t_w1 = (const float*)d_in[10];
  const float* t_b1 = (const float*)d_in[11];
  const float* t_g  = (const float*)d_in[12];
  const float* t_be = (const float*)d_in[13];
  const float* t_m  = (const float*)d_in[14];
  const float* t_v  = (const float*)d_in[15];
  const float* t_w2 = (const float*)d_in[16];
  const float* t_b2 = (const float*)d_in[17];

  char* ws = (char*)d_ws;
  u16* hR = (u16*)ws;                          // [4][289][64] bf16 (pixel-major)
  u16* hT = hR + (size_t)4*289*64;             // [4][289][64] bf16 (pixel-major)
  u16* rlq = (u16*)(ws + 295936);              // [4][289][1024] bf16 (x0.125*log2e)
  float* tlq = (float*)(ws + 295936 + 2367488);// [4][289][48] f32
  float* outp = (float*)d_out;

  hipLaunchKernelGGL(conv1_k, dim3(128), dim3(256), 0, stream,
      p_low, r_w1, r_b1, r_g, r_be, r_m, r_v,
      t_w1, t_b1, t_g, t_be, t_m, t_v, hR, hT);
  hipLaunchKernelGGL(conv2_k, dim3(268), dim3(256), 0, stream,
      hR, hT, r_w2, r_b2, t_w2, t_b2, rlq, tlq);
  hipLaunchKernelGGL(attn_k, dim3(16, 16, 4), dim3(256), 0, stream,
      feature, rlq, tlq, outp);
}

// Round 10
// 434.066 us; speedup vs baseline: 1.0269x; 1.0057x over previous
//
#include <hip/hip_runtime.h>

typedef unsigned short u16;
typedef __bf16 bf16x8 __attribute__((ext_vector_type(8)));
typedef unsigned short us8 __attribute__((ext_vector_type(8)));
typedef float f32x4 __attribute__((ext_vector_type(4)));
typedef float f32x2 __attribute__((ext_vector_type(2)));
typedef unsigned int u32x4 __attribute__((ext_vector_type(4)));

union U8u { us8 s; u16 u[8]; };

__device__ __forceinline__ u16 f2bf(float f){
  unsigned u = __builtin_bit_cast(unsigned, f);
  u += 0x7fffu + ((u >> 16) & 1u);
  return (u16)(u >> 16);
}
__device__ __forceinline__ bf16x8 asbf(us8 x){ return __builtin_bit_cast(bf16x8, x); }

#define MFMA16(a,b,c) __builtin_amdgcn_mfma_f32_16x16x32_bf16((a),(b),(c),0,0,0)

// ---------------------------------------------------------------------------
// Conv: 3x3 SAME on 17x17, Cin=64, im2col GEMM, K' = tap*64 + cin.
// LDS sS: PIXEL-major zero-padded [19*19][72] bf16; sW: [cout 16][584] bf16.
// h workspace is PIXEL-major [b][pix][64] so conv2 staging is a straight copy.
// ---------------------------------------------------------------------------
__device__ __forceinline__ void stage_zero2(u16* sS, int tid){
  uint* z = (uint*)sS;
  for (int i = tid; i < 12996; i += 256) z[i] = 0u;   // 361*72 u16
}

__device__ __forceinline__ void stage_src_f32T(const float* __restrict__ src,
                                               u16* sS, int tid){
  for (int i4 = tid; i4 < 4624; i4 += 256){           // 64*289/4
    int e = i4 * 4;
    f32x4 dv = *(const f32x4*)(src + e);
    #pragma unroll
    for (int t = 0; t < 4; t++){
      int ee = e + t;
      int ci = ee / 289; int rr = ee - ci*289;
      int oy = rr / 17;  int ox = rr - oy*17;
      sS[((oy+1)*19 + ox+1)*72 + ci] = f2bf(dv[t]);
    }
  }
}

// pixel-major bf16 source [pix][64] -> one us8 load + one ds_write_b128 per 8
__device__ __forceinline__ void stage_src_pm(const u16* __restrict__ src,
                                             u16* sS, int tid){
  for (int i8 = tid; i8 < 2312; i8 += 256){           // 289*64/8
    int pix = i8 >> 3, c0 = (i8 & 7) << 3;
    us8 v = *(const us8*)(src + ((size_t)pix << 6) + c0);
    int oy = pix / 17, ox = pix - oy*17;
    *(us8*)(sS + ((oy+1)*19 + ox+1)*72 + c0) = v;
  }
}

__device__ __forceinline__ void stage_w_f32(const float* __restrict__ w, int m0,
                                            u16* sW, int tid){
  for (int i4 = tid; i4 < 2304; i4 += 256){           // 16*576/4
    int e = i4 * 4;
    int co = e / 576; int r0 = e - co*576;
    f32x4 wv = *(const f32x4*)(w + (size_t)(m0+co)*576 + r0);
    #pragma unroll
    for (int t = 0; t < 4; t++){
      int r = r0 + t; int cin = r / 9; int tap = r - cin*9;
      sW[co*584 + tap*64 + cin] = f2bf(wv[t]);
    }
  }
}

__device__ __forceinline__ f32x4 conv_tile2(const u16* sS, const u16* sW,
                                            int nt, int l15, int q)
{
  int p = nt*16 + l15; int pc = p > 288 ? 288 : p;
  int oy = pc / 17, ox = pc - oy*17;
  f32x4 acc = {0.f, 0.f, 0.f, 0.f};
  #pragma unroll
  for (int ks = 0; ks < 18; ks++){
    const int tap = ks >> 1;
    const int dy = tap / 3, dx = tap - dy*3;
    int pix2 = (oy+dy)*19 + (ox+dx);
    us8 bv = *(const us8*)(sS + pix2*72 + (ks & 1)*32 + q*8);
    us8 av = *(const us8*)(sW + l15*584 + ks*32 + q*8);
    acc = MFMA16(asbf(av), asbf(bv), acc);     // A: m=cout(l15); B: n=pix(l15)
  }
  return acc;
}

// conv1 + BN + SiLU -> bf16 h (pixel-major). grid = 128: [job:1][b:2][m:2][px:2]
__global__ __launch_bounds__(256) void conv1_k(
    const float* __restrict__ p_low,
    const float* __restrict__ wR, const float* __restrict__ b1R,
    const float* __restrict__ gR, const float* __restrict__ beR,
    const float* __restrict__ mR, const float* __restrict__ vR,
    const float* __restrict__ wT, const float* __restrict__ b1T,
    const float* __restrict__ gT, const float* __restrict__ beT,
    const float* __restrict__ mT, const float* __restrict__ vT,
    u16* __restrict__ hR, u16* __restrict__ hT)
{
  __shared__ __attribute__((aligned(16))) u16 sS[25992];
  __shared__ __attribute__((aligned(16))) u16 sW[9344];
  int tid = threadIdx.x;
  int bx = blockIdx.x;
  int job = bx >> 6;
  int b = (bx >> 4) & 3;
  int m0 = ((bx >> 2) & 3) << 4;
  int px = bx & 3;
  int nt0 = px * 5, ntEnd = nt0 + 5 > 19 ? 19 : nt0 + 5;
  const float* w  = job ? wT  : wR;
  const float* b1 = job ? b1T : b1R;
  const float* g  = job ? gT  : gR;
  const float* be = job ? beT : beR;
  const float* mn = job ? mT  : mR;
  const float* vr = job ? vT  : vR;
  u16* out = job ? hT : hR;
  const float* src = p_low + (size_t)b * 18496;

  stage_zero2(sS, tid);
  __syncthreads();
  stage_src_f32T(src, sS, tid);
  stage_w_f32(w, m0, sW, tid);
  __syncthreads();

  int lane = tid & 63, wave = tid >> 6;
  int l15 = lane & 15, q = lane >> 4;
  float scl[4], sft[4];
  #pragma unroll
  for (int e = 0; e < 4; e++){
    int co = m0 + q*4 + e;
    float s = g[co] / sqrtf(vr[co] + 1e-5f);
    scl[e] = s;
    sft[e] = (b1[co] - mn[co]) * s + be[co];
  }
  for (int nt = nt0 + wave; nt < ntEnd; nt += 4){
    f32x4 acc = conv_tile2(sS, sW, nt, l15, q);
    int p = nt*16 + l15;
    if (p < 289){
      float si[4];
      #pragma unroll
      for (int e = 0; e < 4; e++){
        float y = acc[e]*scl[e] + sft[e];
        si[e] = y / (1.f + __expf(-y));      // SiLU
      }
      uint2 pk;
      pk.x = (uint)f2bf(si[0]) | ((uint)f2bf(si[1]) << 16);
      pk.y = (uint)f2bf(si[2]) | ((uint)f2bf(si[3]) << 16);
      *(uint2*)(out + ((size_t)b*289 + p)*64 + m0 + q*4) = pk;
    }
  }
}

// conv2 (+bias): r-branch -> rlq bf16 [b][pix][1024] pre-scaled by
//   0.125*log2(e); t-branch -> tlq f32 [b][pix][48].
// grid = 268: r: 4b x 64m = 256;  t: 4b x 3m = 12.
__global__ __launch_bounds__(256) void conv2_k(
    const u16* __restrict__ hR, const u16* __restrict__ hT,
    const float* __restrict__ w2R, const float* __restrict__ b2R,
    const float* __restrict__ w2T, const float* __restrict__ b2T,
    u16* __restrict__ rlq, float* __restrict__ tlq)
{
  __shared__ __attribute__((aligned(16))) u16 sS[25992];
  __shared__ __attribute__((aligned(16))) u16 sW[9344];
  int tid = threadIdx.x;
  int bx = blockIdx.x;
  const float *w, *bias; const u16* src;
  int b, m0, isR;
  if (bx < 256){
    isR = 1; b = bx >> 6; m0 = (bx & 63) << 4;
    src = hR + (size_t)b*18496; w = w2R; bias = b2R;
  } else {
    isR = 0; int i = bx - 256; b = i / 3; m0 = (i - b*3) << 4;
    src = hT + (size_t)b*18496; w = w2T; bias = b2T;
  }

  stage_zero2(sS, tid);
  __syncthreads();
  stage_src_pm(src, sS, tid);
  stage_w_f32(w, m0, sW, tid);
  __syncthreads();

  int lane = tid & 63, wave = tid >> 6;
  int l15 = lane & 15, q = lane >> 4;
  float bs[4];
  #pragma unroll
  for (int e = 0; e < 4; e++) bs[e] = bias[m0 + q*4 + e];
  const float PSC = 0.18033688f;   // 0.125 * log2(e)
  for (int nt = wave; nt < 19; nt += 4){
    f32x4 acc = conv_tile2(sS, sW, nt, l15, q);
    int p = nt*16 + l15;
    if (p < 289){
      if (isR){
        uint2 pk;
        pk.x = (uint)f2bf((acc[0]+bs[0])*PSC)
             | ((uint)f2bf((acc[1]+bs[1])*PSC) << 16);
        pk.y = (uint)f2bf((acc[2]+bs[2])*PSC)
             | ((uint)f2bf((acc[3]+bs[3])*PSC) << 16);
        *(uint2*)(rlq + ((size_t)b*289 + p)*1024 + m0 + q*4) = pk;
      } else {
        f32x4 ov = {acc[0]+bs[0], acc[1]+bs[1], acc[2]+bs[2], acc[3]+bs[3]};
        *(f32x4*)(tlq + ((size_t)b*289 + p)*48 + m0 + q*4) = ov;
      }
    }
  }
}

// ---------------------------------------------------------------------------
// Attention v3 (last-known-good, R7): block per (b, tx, ty). Feature tile
// staged via coalesced global_load_lds into a PING-PONG double buffer
// sF[2][4r][64ch][32col]: chunk loop: {ds_read both col-halves into regs}
// -> {issue stage(c+1) into other buffer + sched_barrier} -> {register-only
// compute (tk in VGPRs)} -> __syncthreads (vmcnt(0) drain IS the pipeline
// wait for chunk c+1). Col XOR-swizzle (q<<3) applied on BOTH write
// (pre-swizzled global col) and read. 2 blocks/CU (74 KB LDS).
// ---------------------------------------------------------------------------
__global__ __launch_bounds__(256) void attn_k(
    const uint* __restrict__ feat,
    const u16* __restrict__ rlq, const float* __restrict__ tlq,
    float* __restrict__ out)
{
  __shared__ __attribute__((aligned(16))) u16 rkT[4608];  // [key=64][72]
  __shared__ __attribute__((aligned(16))) float tkF[256]; // [c=4][key=64]
  __shared__ __attribute__((aligned(1024))) uint sF[2][8192]; // 2x[4][64][32] f32
  int tid = threadIdx.x;
  int ty = blockIdx.x, tx = blockIdx.y, b = blockIdx.z;
  int lane = tid & 63, wave = tid >> 6;
  int l15 = lane & 15, q = lane >> 4;

  { // rk: wave = corner; thread covers couts (lane*16..+16)
    int corner = wave;
    int pix = (tx + (corner >> 1))*17 + ty + (corner & 1);
    const u16* sp = rlq + ((size_t)b*289 + pix)*1024 + lane*16;
    U8u v0, v1; v0.s = *(const us8*)sp; v1.s = *(const us8*)(sp + 8);
    #pragma unroll
    for (int nl = 0; nl < 8; nl++){
      rkT[(corner*16 + nl)*72 + lane]     = v0.u[nl];
      rkT[(corner*16 + 8 + nl)*72 + lane] = v1.u[nl];
    }
  }
  if (tid < 192){
    int corner = tid / 48; int idx = tid - corner*48;
    int pix = (tx + (corner >> 1))*17 + ty + (corner & 1);
    int c = idx >> 4, nl = idx & 15;
    tkF[c*64 + corner*16 + nl] = tlq[((size_t)b*289 + pix)*48 + idx];
  }
  __syncthreads();

  bf16x8 frk[4][2];
  #pragma unroll
  for (int nt = 0; nt < 4; nt++)
    #pragma unroll
    for (int ks = 0; ks < 2; ks++)
      frk[nt][ks] = __builtin_bit_cast(bf16x8,
          *(const us8*)(rkT + (nt*16 + l15)*72 + ks*32 + q*8));

  // tk weights hoisted to registers: NO LDS reads inside the chunk loop's
  // compute, so nothing can force an early vmcnt wait on the prefetch.
  f32x4 tkc[3][4];
  #pragma unroll
  for (int c = 0; c < 3; c++)
    #pragma unroll
    for (int nt = 0; nt < 4; nt++)
      tkc[c][nt] = *(const f32x4*)(tkF + c*64 + nt*16 + q*4);

  const size_t HW = (size_t)512*512;
  // staging lane constants: seg = p*32 + segl covers (i = seg>>6, ch = seg&63)
  int segl = (wave << 3) + (lane >> 3);
  int part = lane & 7;

  #define STAGE(c_, bb_)                                                     \
    _Pragma("unroll")                                                        \
    for (int p = 0; p < 8; ++p){                                             \
      int seg = p*32 + segl;                                                 \
      int i  = seg >> 6;                                                     \
      int ch = seg & 63;                                                     \
      int qq = (ch >> 3) & 3;                                                \
      int col0 = ((part ^ (qq << 1)) << 2);                                  \
      const uint* src = feat + ((size_t)(b*64 + ch))*HW                      \
                      + (size_t)(tx*32 + i*8 + (c_))*512 + (ty*32 + col0);   \
      uint* dst = sF[bb_] + (size_t)(p*32 + (wave << 3))*32;                 \
      __builtin_amdgcn_global_load_lds(                                      \
          (const __attribute__((address_space(1))) void*)src,                \
          (__attribute__((address_space(3))) void*)dst, 16, 0, 0);           \
    }

  STAGE(0, 0);
  __syncthreads();   // chunk 0 resident

  for (int c = 0; c < 8; ++c){
    int bb = c & 1;
    // ---- ds-read both col-halves of this wave's row into registers ----
    uint r0[2][8], r1[2][8];
    #pragma unroll
    for (int h = 0; h < 2; ++h){
      int colL = ((h << 4) + l15) ^ (q << 3);  // same XOR as write side
      const uint* fp = sF[bb] + wave*2048 + q*256 + colL;
      #pragma unroll
      for (int j = 0; j < 8; j++){
        r0[h][j] = fp[j*32];          // ch q*8+j   (f32 bits)
        r1[h][j] = fp[1024 + j*32];   // ch 32+q*8+j
      }
    }
    // ---- issue next chunk into the other buffer; pin issue point ----
    if (c < 7){ STAGE(c+1, bb^1); }
    __builtin_amdgcn_sched_barrier(0);

    // ---- register-only compute for both halves ----
    #pragma unroll
    for (int h = 0; h < 2; ++h){
      u32x4 p0v, p1v;
      #pragma unroll
      for (int j2 = 0; j2 < 4; j2++){
        p0v[j2] = __builtin_amdgcn_perm(r0[h][2*j2+1], r0[h][2*j2], 0x07060302u);
        p1v[j2] = __builtin_amdgcn_perm(r1[h][2*j2+1], r1[h][2*j2], 0x07060302u);
      }
      bf16x8 A0 = __builtin_bit_cast(bf16x8, p0v);  // ch  0..31, pixel l15
      bf16x8 A1 = __builtin_bit_cast(bf16x8, p1v);  // ch 32..63

      f32x4 acc[4];
      #pragma unroll
      for (int nt = 0; nt < 4; nt++){
        f32x4 zz = {0.f, 0.f, 0.f, 0.f};
        zz = MFMA16(frk[nt][0], A0, zz);   // A = keys, B = feature
        zz = MFMA16(frk[nt][1], A1, zz);
        acc[nt] = zz;
      }

      // lane-local PV: p = exp2(score), o[c] += p*tk, den += p
      f32x2 den2 = {0.f,0.f}, o0v = {0.f,0.f}, o1v = {0.f,0.f}, o2v = {0.f,0.f};
      #pragma unroll
      for (int nt = 0; nt < 4; nt++){
        f32x2 pa, pb;
        pa[0] = __builtin_amdgcn_exp2f(acc[nt][0]);
        pa[1] = __builtin_amdgcn_exp2f(acc[nt][1]);
        pb[0] = __builtin_amdgcn_exp2f(acc[nt][2]);
        pb[1] = __builtin_amdgcn_exp2f(acc[nt][3]);
        den2 += pa; den2 += pb;
        f32x2 t0a = {tkc[0][nt][0], tkc[0][nt][1]};
        f32x2 t0b = {tkc[0][nt][2], tkc[0][nt][3]};
        f32x2 t1a = {tkc[1][nt][0], tkc[1][nt][1]};
        f32x2 t1b = {tkc[1][nt][2], tkc[1][nt][3]};
        f32x2 t2a = {tkc[2][nt][0], tkc[2][nt][1]};
        f32x2 t2b = {tkc[2][nt][2], tkc[2][nt][3]};
        o0v = __builtin_elementwise_fma(pa, t0a, o0v);
        o0v = __builtin_elementwise_fma(pb, t0b, o0v);
        o1v = __builtin_elementwise_fma(pa, t1a, o1v);
        o1v = __builtin_elementwise_fma(pb, t1b, o1v);
        o2v = __builtin_elementwise_fma(pa, t2a, o2v);
        o2v = __builtin_elementwise_fma(pb, t2b, o2v);
      }
      float den = den2[0] + den2[1];
      float o0 = o0v[0] + o0v[1];
      float o1 = o1v[0] + o1v[1];
      float o2 = o2v[0] + o2v[1];
      // reduce over the 4 q-groups: xor 16, xor 32
      o0  += __shfl_xor(o0, 16, 64);
      o1  += __shfl_xor(o1, 16, 64);
      o2  += __shfl_xor(o2, 16, 64);
      den += __shfl_xor(den, 16, 64);
      o0  += __shfl_xor(o0, 32, 64);
      o1  += __shfl_xor(o1, 32, 64);
      o2  += __shfl_xor(o2, 32, 64);
      den += __shfl_xor(den, 32, 64);
      float rin = __builtin_amdgcn_rcpf(den);
      float val = (q == 0) ? o0 : ((q == 1) ? o1 : o2);
      int hh = tx*32 + wave*8 + c;
      int j0 = h << 4;
      if (q < 3)
        out[((size_t)(b*3 + q)*512 + hh)*512 + (ty*32 + j0 + l15)] = val * rin;
    }
    __syncthreads();   // vmcnt(0) drain = wait for chunk c+1; frees buf bb
  }
  #undef STAGE
}

extern "C" void kernel_launch(void* const* d_in, const int* in_sizes, int n_in,
                              void* d_out, int out_size, void* d_ws, size_t ws_size,
                              hipStream_t stream)
{
  (void)in_sizes; (void)n_in; (void)out_size; (void)ws_size;
  const uint*  feature = (const uint*)d_in[0];
  const float* p_low = (const float*)d_in[1];
  const float* r_w1 = (const float*)d_in[2];
  const float* r_b1 = (const float*)d_in[3];
  const float* r_g  = (const float*)d_in[4];
  const float* r_be = (const float*)d_in[5];
  const float* r_m  = (const float*)d_in[6];
  const float* r_v  = (const float*)d_in[7];
  const float* r_w2 = (const float*)d_in[8];
  const float* r_b2 = (const float*)d_in[9];
  const float* t_w1 = (const float*)d_in[10];
  const float* t_b1 = (const float*)d_in[11];
  const float* t_g  = (const float*)d_in[12];
  const float* t_be = (const float*)d_in[13];
  const float* t_m  = (const float*)d_in[14];
  const float* t_v  = (const float*)d_in[15];
  const float* t_w2 = (const float*)d_in[16];
  const float* t_b2 = (const float*)d_in[17];

  char* ws = (char*)d_ws;
  u16* hR = (u16*)ws;                          // [4][289][64] bf16 (pixel-major)
  u16* hT = hR + (size_t)4*289*64;             // [4][289][64] bf16 (pixel-major)
  u16* rlq = (u16*)(ws + 295936);              // [4][289][1024] bf16 (x0.125*log2e)
  float* tlq = (float*)(ws + 295936 + 2367488);// [4][289][48] f32
  float* outp = (float*)d_out;

  hipLaunchKernelGGL(conv1_k, dim3(128), dim3(256), 0, stream,
      p_low, r_w1, r_b1, r_g, r_be, r_m, r_v,
      t_w1, t_b1, t_g, t_be, t_m, t_v, hR, hT);
  hipLaunchKernelGGL(conv2_k, dim3(268), dim3(256), 0, stream,
      hR, hT, r_w2, r_b2, t_w2, t_b2, rlq, tlq);
  hipLaunchKernelGGL(attn_k, dim3(16, 16, 4), dim3(256), 0, stream,
      feature, rlq, tlq, outp);
}